// Round 4
// baseline (326.298 us; speedup 1.0000x reference)
//
#include <hip/hip_runtime.h>

#define NN 10000
#define CC 128
#define HH 256
#define EE 320000
#define ETILE 128
#define EBLOCKS 2500  // EE/128 exact, no pad

typedef __bf16 bf16_t;
typedef __bf16 bf16x8 __attribute__((ext_vector_type(8)));
typedef __bf16 bf16x4 __attribute__((ext_vector_type(4)));
typedef float f32x4 __attribute__((ext_vector_type(4)));

__device__ __forceinline__ float silu_f(float v) {
#if __has_builtin(__builtin_amdgcn_rcpf)
  return v * __builtin_amdgcn_rcpf(1.0f + __expf(-v));
#else
  return v / (1.0f + __expf(-v));
#endif
}

// ---- GEMM slab helper (16x16x32 bf16 MFMA) ----
// Fragment layouts (guide §3, m89-verified):
//   1st operand: lane holds A[m=lane&15][k=quad*8+j]
//   2nd operand: lane holds B[k=quad*8+j][n=lane&15]
//   C/D: col(n)=lane&15, row(m)=quad*4+reg
template<int RE, int KD, int SA, int NT>
__device__ __forceinline__ void gemm_lg(const bf16_t* sAa, const bf16_t* __restrict__ BT,
                                        int nwavebase, int lr, int quad, f32x4 acc[RE][NT]) {
  for (int kk = 0; kk < KD; kk += 32) {
    bf16x8 a[RE]; bf16x8 b[NT];
#pragma unroll
    for (int re = 0; re < RE; re++)
      a[re] = *(const bf16x8*)(sAa + (re * 16 + lr) * SA + kk + quad * 8);
#pragma unroll
    for (int ce = 0; ce < NT; ce++)
      b[ce] = *(const bf16x8*)(BT + (size_t)(nwavebase + ce * 16 + lr) * KD + kk + quad * 8);
#pragma unroll
    for (int re = 0; re < RE; re++)
#pragma unroll
      for (int ce = 0; ce < NT; ce++)
        acc[re][ce] = __builtin_amdgcn_mfma_f32_16x16x32_bf16(a[re], b[ce], acc[re][ce], 0, 0, 0);
  }
}

// ---------- prep: 6 weight transposes + zero sums/cnt ----------
__global__ __launch_bounds__(256) void prep_kernel(
    const float* __restrict__ We1, const float* __restrict__ We2,
    const float* __restrict__ Wn1, const float* __restrict__ Wn2,
    const float* __restrict__ Wm1, const float* __restrict__ Wm2,
    bf16_t* __restrict__ We1T, bf16_t* __restrict__ We2T,
    bf16_t* __restrict__ Wn1T, bf16_t* __restrict__ Wn2T,
    bf16_t* __restrict__ Wm1T, bf16_t* __restrict__ Wm2T,
    float* __restrict__ sums, int* __restrict__ cnt) {
  int i = blockIdx.x * 256 + threadIdx.x;
  if (i < 327680) {
    const float* src; bf16_t* dst; int K, Nc, idx;
    if      (i < 65536)  { src = We1; dst = We1T; K = 256; Nc = 256; idx = i; }
    else if (i < 131072) { src = We2; dst = We2T; K = 256; Nc = 256; idx = i - 65536; }
    else if (i < 229376) { src = Wn1; dst = Wn1T; K = 384; Nc = 256; idx = i - 131072; }
    else if (i < 262144) { src = Wn2; dst = Wn2T; K = 256; Nc = 128; idx = i - 229376; }
    else if (i < 294912) { src = Wm1; dst = Wm1T; K = 128; Nc = 256; idx = i - 262144; }
    else                 { src = Wm2; dst = Wm2T; K = 256; Nc = 128; idx = i - 294912; }
    int n = idx / K, k = idx - n * K;
    dst[idx] = (bf16_t)src[(size_t)k * Nc + n];
  } else if (i < 327680 + 640000) {  // NN*HH/4 f32x4 zeros
    f32x4 z = {0.f, 0.f, 0.f, 0.f};
    ((f32x4*)sums)[i - 327680] = z;
  } else if (i < 327680 + 640000 + 2500) {  // NN/4 int4 zeros
    int4 z = {0, 0, 0, 0};
    ((int4*)cnt)[i - 967680] = z;
  }
}

// ---------- fused LN1 + P/Q precompute, 16 nodes/block, 625 blocks ----------
// hn = LN(h,g1,bt1) -> hn16
// PQ[n][0:256]   = hn[n] @ We1[0:128,:] + be1   (P, be1 folded)
// PQ[n][256:512] = hn[n] @ We1[128:256,:]       (Q)
__global__ __launch_bounds__(256, 4) void node_pre_kernel(
    const float* __restrict__ h, const float* __restrict__ g1,
    const float* __restrict__ bt1,
    const bf16_t* __restrict__ We1T, const float* __restrict__ be1,
    bf16_t* __restrict__ hn16, bf16_t* __restrict__ PQ) {
  __shared__ __align__(16) bf16_t sHn[16 * 136];
  int tid = threadIdx.x;
  int lane = tid & 63, wave = tid >> 6;
  int lr = lane & 15, quad = lane >> 4;
  int n0 = blockIdx.x * 16;  // 625 * 16 = NN exact

  // LN1: 16 threads/node, 8 channels each
  {
    int node = tid >> 4, c0 = (tid & 15) * 8;
    size_t base = (size_t)(n0 + node) * CC;
    f32x4 u0 = *(const f32x4*)(h + base + c0);
    f32x4 u1 = *(const f32x4*)(h + base + c0 + 4);
    float s = 0.f, sq = 0.f;
#pragma unroll
    for (int j = 0; j < 4; j++) { s += u0[j] + u1[j]; sq += u0[j] * u0[j] + u1[j] * u1[j]; }
#pragma unroll
    for (int o = 8; o > 0; o >>= 1) { s += __shfl_xor(s, o); sq += __shfl_xor(sq, o); }
    float mu = s * (1.0f / CC);
    float var = sq * (1.0f / CC) - mu * mu;
    float rs = rsqrtf(var + 1e-5f);
    f32x4 gg0 = *(const f32x4*)(g1 + c0), gg1 = *(const f32x4*)(g1 + c0 + 4);
    f32x4 bb0 = *(const f32x4*)(bt1 + c0), bb1 = *(const f32x4*)(bt1 + c0 + 4);
    bf16x8 ov;
#pragma unroll
    for (int j = 0; j < 4; j++) {
      ov[j] = (bf16_t)((u0[j] - mu) * rs * gg0[j] + bb0[j]);
      ov[j + 4] = (bf16_t)((u1[j] - mu) * rs * gg1[j] + bb1[j]);
    }
    *(bf16x8*)(sHn + node * 136 + c0) = ov;
    *(bf16x8*)(hn16 + base + c0) = ov;
  }
  __syncthreads();

  // PQ GEMM: waves 0-1 -> P (We1T k-cols 0:128), waves 2-3 -> Q (k-cols 128:256).
  bool isQ = wave >= 2;
  int rbase = (wave & 1) * 128;
  int koff = isQ ? 128 : 0;
  f32x4 zf = {0.f, 0.f, 0.f, 0.f};
  f32x4 acc[8];
#pragma unroll
  for (int i = 0; i < 8; i++) acc[i] = zf;
  for (int kk = 0; kk < 128; kk += 32) {
    bf16x8 b = *(const bf16x8*)(sHn + lr * 136 + kk + quad * 8);
    bf16x8 a[8];
#pragma unroll
    for (int re = 0; re < 8; re++)
      a[re] = *(const bf16x8*)(We1T + (size_t)(rbase + re * 16 + lr) * 256 + koff + kk + quad * 8);
#pragma unroll
    for (int re = 0; re < 8; re++)
      acc[re] = __builtin_amdgcn_mfma_f32_16x16x32_bf16(a[re], b, acc[re], 0, 0, 0);
  }
  // C: col = node (lr), row = channel rbase + re*16 + quad*4 + r
#pragma unroll
  for (int re = 0; re < 8; re++) {
    int cb = rbase + re * 16 + quad * 4;
    f32x4 bb = isQ ? zf : *(const f32x4*)(be1 + cb);
    bf16x4 o;
#pragma unroll
    for (int r = 0; r < 4; r++) o[r] = (bf16_t)(acc[re][r] + bb[r]);
    *(bf16x4*)(PQ + (size_t)(n0 + lr) * 512 + (isQ ? 256 : 0) + cb) = o;
  }
}

// ---------- CSR build ----------
__global__ __launch_bounds__(256) void count_kernel(const int* __restrict__ ei, int* __restrict__ cnt) {
  int e = blockIdx.x * 256 + threadIdx.x;
  atomicAdd(&cnt[ei[EE + e]], 1);
}

// single-pass scan: thread owns 10 contiguous elements
__global__ __launch_bounds__(1024) void scan_kernel(const int* __restrict__ cnt, int* __restrict__ cursor) {
  __shared__ int wsum[16];
  int tid = threadIdx.x, wave = tid >> 6, lane = tid & 63;
  int base = tid * 10;
  int v[10]; int S = 0;
#pragma unroll
  for (int j = 0; j < 10; j++) {
    int i = base + j;
    v[j] = (i < NN) ? cnt[i] : 0;
    S += v[j];
  }
  int s = S;
#pragma unroll
  for (int off = 1; off < 64; off <<= 1) { int t = __shfl_up(s, off); if (lane >= off) s += t; }
  if (lane == 63) wsum[wave] = s;
  __syncthreads();
  if (tid < 16) {
    int ws = wsum[tid];
#pragma unroll
    for (int off = 1; off < 16; off <<= 1) { int t = __shfl_up(ws, off); if (tid >= off) ws += t; }
    wsum[tid] = ws;
  }
  __syncthreads();
  int ex = ((wave > 0) ? wsum[wave - 1] : 0) + s - S;  // exclusive prefix of this chunk
#pragma unroll
  for (int j = 0; j < 10; j++) {
    int i = base + j;
    if (i < NN) cursor[i] = ex;
    ex += v[j];
  }
}

__global__ __launch_bounds__(256) void scatter_kernel(const int* __restrict__ ei,
                                                      const float* __restrict__ x,
                                                      int* __restrict__ cursor,
                                                      uint4* __restrict__ edat) {
  int e = blockIdx.x * 256 + threadIdx.x;
  int r = ei[e], c = ei[EE + e];
  float dx = x[3 * r] - x[3 * c];
  float dy = x[3 * r + 1] - x[3 * c + 1];
  float dz = x[3 * r + 2] - x[3 * c + 2];
  float d = sqrtf(dx * dx + dy * dy + dz * dz);
  float cc = (d <= 5.0f) ? 0.5f * (cosf(d * 0.6283185307179586f) + 1.0f) : 0.0f;
  int pos = atomicAdd(&cursor[c], 1);
  uint4 v = {(unsigned)r, (unsigned)c, __float_as_uint(d), __float_as_uint(cc)};
  edat[pos] = v;
}

// ---------- edge kernel: 128-edge tiles, two-half T14 pipeline ----------
// Round-3 lesson: ~70% of block latency is stall; PQ gather (random P rows,
// L2-miss ~600cy) is the un-attacked source. Split tile into halves A/B:
// B's gathers are issued right before GEMM-A and consumed in m1-B after it,
// hiding B's gather latency under GEMM-A's MFMA+LDS work. VGPR budget:
// accA(32)+B-flight(32)+frags(24)+base ~118 <= 128 -> 2 blocks/CU kept.
__global__ __launch_bounds__(512, 4) void edge_mlp_kernel(
    const uint4* __restrict__ edat, const bf16_t* __restrict__ PQ,
    const float* __restrict__ We1last,
    const bf16_t* __restrict__ We2T, const float* __restrict__ be2,
    float* __restrict__ sums) {
  __shared__ __align__(512) bf16_t sM1[ETILE * 256];  // 64 KB, swizzled rows
  __shared__ int sRow[ETILE], sCol[ETILE];
  __shared__ float sD[ETILE], sCc[ETILE];
  __shared__ unsigned long long sMaskA, sMaskB;
  int tid = threadIdx.x;
  int lane = tid & 63, wave = tid >> 6;
  int lr = lane & 15, quad = lane >> 4;

  // T1 bijective XCD-chunked swizzle (m204): nwg=2500 = 8*312 + 4.
  int bid = blockIdx.x;
  int xcd = bid & 7, rank = bid >> 3;
  int swz = (xcd < 4 ? xcd * 313 : 4 * 313 + (xcd - 4) * 312) + rank;
  int e0 = swz * ETILE;

  if (tid < ETILE) {
    uint4 v = edat[e0 + tid];
    sRow[tid] = (int)v.x; sCol[tid] = (int)v.y;
    sD[tid] = __uint_as_float(v.z); sCc[tid] = __uint_as_float(v.w);
  }
  __syncthreads();

  if (tid < ETILE) {  // waves 0,1 compute segment-boundary masks
    int fl = (tid > 0) && (sCol[tid] != sCol[tid - 1]);
    unsigned long long m = __ballot(fl);
    if (tid == 0) sMaskA = m;       // edges 1..63
    if (tid == 64) sMaskB = m;      // edges 64..127 (bit j = edge 64+j)
  }

  // Per-thread chunk mapping: col block k0 fixed, edge rows step by 16.
  int ebase = tid >> 5;        // 0..15
  int k0 = (tid & 31) * 8;     // bf16 element offset within 256-ch row
  f32x4 wl0 = *(const f32x4*)(We1last + k0);
  f32x4 wl1 = *(const f32x4*)(We1last + k0 + 4);

  auto m1_compute = [&](int e, const bf16x8& pv, const bf16x8& qv) {
    float d = sD[e];
    bf16x8 m;
#pragma unroll
    for (int j = 0; j < 4; j++) {
      m[j] = (bf16_t)silu_f((float)pv[j] + (float)qv[j] + d * wl0[j]);
      m[j + 4] = (bf16_t)silu_f((float)pv[j + 4] + (float)qv[j + 4] + d * wl1[j]);
    }
    int boff = ((e << 9) + (k0 << 1)) ^ ((e & 7) << 4);
    *(bf16x8*)((char*)sM1 + boff) = m;
  };

  // half A: issue gathers, compute m1 rows 0..63
  {
    bf16x8 pvA[4], qvA[4];
#pragma unroll
    for (int i = 0; i < 4; i++) {
      int e = ebase + i * 16;
      pvA[i] = *(const bf16x8*)(PQ + (size_t)sRow[e] * 512 + k0);
      qvA[i] = *(const bf16x8*)(PQ + (size_t)sCol[e] * 512 + 256 + k0);
    }
#pragma unroll
    for (int i = 0; i < 4; i++) m1_compute(ebase + i * 16, pvA[i], qvA[i]);
  }
  __syncthreads();

  // issue half-B gathers NOW; they land while GEMM-A runs
  bf16x8 pvB[4], qvB[4];
#pragma unroll
  for (int i = 0; i < 4; i++) {
    int e = 64 + ebase + i * 16;
    pvB[i] = *(const bf16x8*)(PQ + (size_t)sRow[e] * 512 + k0);
    qvB[i] = *(const bf16x8*)(PQ + (size_t)sCol[e] * 512 + 256 + k0);
  }

  f32x4 zf = {0.f, 0.f, 0.f, 0.f};
  f32x4 acc[8][2];
  int nb = wave * 32;

  auto gemm_half = [&](int rbase, int aoff) {
#pragma unroll
    for (int i = 0; i < 4; i++) { acc[aoff + i][0] = zf; acc[aoff + i][1] = zf; }
    for (int kk = 0; kk < 256; kk += 32) {
      bf16x8 a[4], b[2];
#pragma unroll
      for (int re = 0; re < 4; re++) {
        int row = rbase + re * 16 + lr;
        int boff = ((row << 9) + (kk << 1) + (quad << 4)) ^ ((row & 7) << 4);
        a[re] = *(const bf16x8*)((const char*)sM1 + boff);
      }
#pragma unroll
      for (int ce = 0; ce < 2; ce++)
        b[ce] = *(const bf16x8*)(We2T + (size_t)(nb + ce * 16 + lr) * 256 + kk + quad * 8);
#pragma unroll
      for (int re = 0; re < 4; re++)
#pragma unroll
        for (int ce = 0; ce < 2; ce++)
          acc[aoff + re][ce] = __builtin_amdgcn_mfma_f32_16x16x32_bf16(a[re], b[ce], acc[aoff + re][ce], 0, 0, 0);
    }
  };

  // GEMM over rows 0..63 (B gathers in flight underneath)
  gemm_half(0, 0);

  // m1-B: consume gathers (landed), write rows 64..127 (disjoint from GEMM-A reads)
#pragma unroll
  for (int i = 0; i < 4; i++) m1_compute(64 + ebase + i * 16, pvB[i], qvB[i]);
  __syncthreads();

  // GEMM over rows 64..127
  gemm_half(64, 4);

  // in-register epilogue: silu(acc+be2)*cc  (edge e = re*16+quad*4+r)
  float be2v[2];
#pragma unroll
  for (int ce = 0; ce < 2; ce++) be2v[ce] = be2[wave * 32 + ce * 16 + lr];
#pragma unroll
  for (int re = 0; re < 8; re++) {
    f32x4 cc = *(const f32x4*)(sCc + re * 16 + quad * 4);
#pragma unroll
    for (int ce = 0; ce < 2; ce++)
#pragma unroll
      for (int r = 0; r < 4; r++)
        acc[re][ce][r] = silu_f(acc[re][ce][r] + be2v[ce]) * cc[r];
  }

  // register segmented reduction with static tile-skip (wave-uniform branches).
  // Boundary bits: mA bit i (1<=i<=63) = edge i; mB bit j = edge 64+j.
  {
    unsigned long long mA = sMaskA;
    unsigned long long mB = sMaskB;
    int lo = 0;
    while (lo < ETILE) {
      int hi;
      if (lo < 63) {
        unsigned long long t = mA & (~0ull << (lo + 1));
        hi = t ? (__ffsll((long long)t) - 1)
               : (mB ? 64 + __ffsll((long long)mB) - 1 : ETILE);
      } else {
        int rel = lo - 64;  // lo==63 -> rel=-1 -> shift 0 -> all of mB
        unsigned long long t = (rel < 63) ? (mB & (~0ull << (rel + 1))) : 0ull;
        hi = t ? 64 + __ffsll((long long)t) - 1 : ETILE;
      }
      f32x4 tv = zf;
#pragma unroll
      for (int re = 0; re < 8; re++) {
        int t0 = re * 16, t1e = t0 + 16;
        if (t1e <= lo || t0 >= hi) continue;  // tile outside segment (scalar skip)
        if (t0 >= lo && t1e <= hi) {          // tile fully inside: unmasked adds
#pragma unroll
          for (int r = 0; r < 4; r++)
#pragma unroll
            for (int ce = 0; ce < 2; ce++)
              tv[ce] += acc[re][ce][r];
        } else {                              // straddles boundary: masked adds
          int eb = t0 + quad * 4;
#pragma unroll
          for (int r = 0; r < 4; r++) {
            int e = eb + r;
            bool in = (e >= lo) && (e < hi);
#pragma unroll
            for (int ce = 0; ce < 2; ce++)
              tv[ce] += in ? acc[re][ce][r] : 0.0f;
          }
        }
      }
#pragma unroll
      for (int ce = 0; ce < 2; ce++) {
        tv[ce] += __shfl_xor(tv[ce], 16);
        tv[ce] += __shfl_xor(tv[ce], 32);
      }
      if (quad == 0) {
        int colv = sCol[lo];
#pragma unroll
        for (int ce = 0; ce < 2; ce++)
          atomicAdd(&sums[(size_t)colv * HH + wave * 32 + ce * 16 + lr], tv[ce]);
      }
      lo = hi;
    }
  }
}

// ---------- fused node pipeline: 16 nodes/block, 625 blocks ----------
__global__ __launch_bounds__(256, 3) void node_fused_kernel(
    const float* __restrict__ h, const bf16_t* __restrict__ hn16,
    const float* __restrict__ sums, const int* __restrict__ cnt,
    const bf16_t* __restrict__ Wn1T, const float* __restrict__ bn1,
    const bf16_t* __restrict__ Wn2T, const float* __restrict__ bn2,
    const float* __restrict__ g2, const float* __restrict__ bt2,
    const bf16_t* __restrict__ Wm1T, const float* __restrict__ bm1,
    const bf16_t* __restrict__ Wm2T, const float* __restrict__ bm2,
    float* __restrict__ out) {
  __shared__ __align__(16) bf16_t sA1[16 * 392];
  __shared__ __align__(16) bf16_t sM[16 * 264];
  __shared__ __align__(16) float sH1[16 * 132];
  __shared__ __align__(16) bf16_t sLn[16 * 136];
  __shared__ float sRc[16];
  int tid = threadIdx.x;
  int lane = tid & 63, wave = tid >> 6;
  int lr = lane & 15, quad = lane >> 4;
  int n0 = blockIdx.x * 16;  // exact

  if (tid < 16) sRc[tid] = 1.0f / fmaxf((float)cnt[n0 + tid], 1.0f);
  __syncthreads();

  // stage A1 = [hn16 | sums*rc]: 16 nodes x 48 16B-chunks
#pragma unroll
  for (int i = 0; i < 3; i++) {
    int o = tid + i * 256;
    int e = o / 48, q = o - e * 48;
    int node = n0 + e;
    if (q < 16) {
      *(uint4*)(sA1 + e * 392 + q * 8) = *(const uint4*)(hn16 + (size_t)node * CC + q * 8);
    } else {
      float rc = sRc[e];
      const float* sp = sums + (size_t)node * HH + (q - 16) * 8;
      bf16x8 bv;
#pragma unroll
      for (int k2 = 0; k2 < 8; k2++) bv[k2] = (bf16_t)(sp[k2] * rc);
      *(bf16x8*)(sA1 + e * 392 + 128 + (q - 16) * 8) = bv;
    }
  }
  __syncthreads();

  f32x4 zf = {0.f, 0.f, 0.f, 0.f};
  {  // GEMM1: 16x384 @ 384x256 -> silu -> sM
    f32x4 acc[1][4];
#pragma unroll
    for (int j = 0; j < 4; j++) acc[0][j] = zf;
    gemm_lg<1, 384, 392, 4>(sA1, Wn1T, wave * 64, lr, quad, acc);
#pragma unroll
    for (int ce = 0; ce < 4; ce++) {
      int n = wave * 64 + ce * 16 + lr;
      float b1 = bn1[n];
#pragma unroll
      for (int r = 0; r < 4; r++)
        sM[(quad * 4 + r) * 264 + n] = (bf16_t)silu_f(acc[0][ce][r] + b1);
    }
  }
  __syncthreads();

  {  // GEMM2: 16x256 @ 256x128; h1 = h + hn + hd -> sH1
    f32x4 acc[1][2];
    acc[0][0] = zf; acc[0][1] = zf;
    gemm_lg<1, 256, 264, 2>(sM, Wn2T, wave * 32, lr, quad, acc);
#pragma unroll
    for (int ce = 0; ce < 2; ce++) {
      int n = wave * 32 + ce * 16 + lr;
      float b2 = bn2[n];
#pragma unroll
      for (int r = 0; r < 4; r++) {
        int node = quad * 4 + r;
        size_t idx = (size_t)(n0 + node) * CC + n;
        float hn_v = (float)sA1[node * 392 + n];
        sH1[node * 132 + n] = h[idx] + hn_v + acc[0][ce][r] + b2;
      }
    }
  }
  __syncthreads();

  {  // LN2 in-LDS: thread -> node tid>>4, channels (tid&15)*8..+7
    int node = tid >> 4, c0 = (tid & 15) * 8;
    f32x4 u0 = *(const f32x4*)(sH1 + node * 132 + c0);
    f32x4 u1 = *(const f32x4*)(sH1 + node * 132 + c0 + 4);
    float s = 0.f, sq = 0.f;
#pragma unroll
    for (int j = 0; j < 4; j++) { s += u0[j] + u1[j]; sq += u0[j] * u0[j] + u1[j] * u1[j]; }
#pragma unroll
    for (int o = 8; o > 0; o >>= 1) { s += __shfl_xor(s, o); sq += __shfl_xor(sq, o); }
    float mu = s * (1.0f / CC);
    float var = sq * (1.0f / CC) - mu * mu;
    float rs = rsqrtf(var + 1e-5f);
    f32x4 gg0 = *(const f32x4*)(g2 + c0), gg1 = *(const f32x4*)(g2 + c0 + 4);
    f32x4 bb0 = *(const f32x4*)(bt2 + c0), bb1 = *(const f32x4*)(bt2 + c0 + 4);
    bf16x8 ov;
#pragma unroll
    for (int j = 0; j < 4; j++) {
      ov[j] = (bf16_t)((u0[j] - mu) * rs * gg0[j] + bb0[j]);
      ov[j + 4] = (bf16_t)((u1[j] - mu) * rs * gg1[j] + bb1[j]);
    }
    *(bf16x8*)(sLn + node * 136 + c0) = ov;
  }
  __syncthreads();

  {  // GEMM3: 16x128 @ 128x256 -> silu -> sM (reuse)
    f32x4 acc[1][4];
#pragma unroll
    for (int j = 0; j < 4; j++) acc[0][j] = zf;
    gemm_lg<1, 128, 136, 4>(sLn, Wm1T, wave * 64, lr, quad, acc);
#pragma unroll
    for (int ce = 0; ce < 4; ce++) {
      int n = wave * 64 + ce * 16 + lr;
      float b1 = bm1[n];
#pragma unroll
      for (int r = 0; r < 4; r++)
        sM[(quad * 4 + r) * 264 + n] = (bf16_t)silu_f(acc[0][ce][r] + b1);
    }
  }
  __syncthreads();

  {  // GEMM4: 16x256 @ 256x128; out = h1 + hd2
    f32x4 acc[1][2];
    acc[0][0] = zf; acc[0][1] = zf;
    gemm_lg<1, 256, 264, 2>(sM, Wm2T, wave * 32, lr, quad, acc);
#pragma unroll
    for (int ce = 0; ce < 2; ce++) {
      int n = wave * 32 + ce * 16 + lr;
      float b2 = bm2[n];
#pragma unroll
      for (int r = 0; r < 4; r++) {
        int node = quad * 4 + r;
        size_t idx = (size_t)(n0 + node) * CC + n;
        out[idx] = sH1[node * 132 + n] + acc[0][ce][r] + b2;
      }
    }
  }
}

extern "C" void kernel_launch(void* const* d_in, const int* in_sizes, int n_in,
                              void* d_out, int out_size, void* d_ws, size_t ws_size,
                              hipStream_t stream) {
  const float* x    = (const float*)d_in[0];
  const float* h    = (const float*)d_in[1];
  const int*   ei   = (const int*)d_in[2];
  const float* We1  = (const float*)d_in[3];
  const float* be1  = (const float*)d_in[4];
  const float* We2  = (const float*)d_in[5];
  const float* be2  = (const float*)d_in[6];
  const float* Wn1  = (const float*)d_in[7];
  const float* bn1  = (const float*)d_in[8];
  const float* Wn2  = (const float*)d_in[9];
  const float* bn2  = (const float*)d_in[10];
  const float* Wm1  = (const float*)d_in[11];
  const float* bm1  = (const float*)d_in[12];
  const float* Wm2  = (const float*)d_in[13];
  const float* bm2  = (const float*)d_in[14];
  const float* g1   = (const float*)d_in[15];
  const float* bt1  = (const float*)d_in[16];
  const float* g2   = (const float*)d_in[17];
  const float* bt2  = (const float*)d_in[18];
  float* out = (float*)d_out;

  char* wp = (char*)d_ws;
  size_t off = 0;
  auto alloc = [&](size_t bytes) -> void* {
    void* p = wp + off;
    off = (off + bytes + 255) & ~(size_t)255;
    return p;
  };

  bf16_t* hn16   = (bf16_t*)alloc((size_t)NN * CC * 2);
  bf16_t* PQ     = (bf16_t*)alloc((size_t)NN * 512 * 2);
  float*  sums   = (float*)alloc((size_t)NN * HH * 4);
  int*    cnt    = (int*)alloc((size_t)NN * 4);
  int*    cursor = (int*)alloc((size_t)NN * 4);
  uint4*  edat   = (uint4*)alloc((size_t)EE * 16);
  bf16_t* We1T   = (bf16_t*)alloc(256 * 256 * 2);
  bf16_t* We2T   = (bf16_t*)alloc(256 * 256 * 2);
  bf16_t* Wn1T   = (bf16_t*)alloc(256 * 384 * 2);
  bf16_t* Wn2T   = (bf16_t*)alloc(128 * 256 * 2);
  bf16_t* Wm1T   = (bf16_t*)alloc(256 * 128 * 2);
  bf16_t* Wm2T   = (bf16_t*)alloc(128 * 256 * 2);

  prep_kernel<<<3791, 256, 0, stream>>>(We1, We2, Wn1, Wn2, Wm1, Wm2,
                                        We1T, We2T, Wn1T, Wn2T, Wm1T, Wm2T,
                                        sums, cnt);

  node_pre_kernel<<<NN / 16, 256, 0, stream>>>(h, g1, bt1, We1T, be1, hn16, PQ);

  count_kernel<<<EE / 256, 256, 0, stream>>>(ei, cnt);
  scan_kernel<<<1, 1024, 0, stream>>>(cnt, cursor);
  scatter_kernel<<<EE / 256, 256, 0, stream>>>(ei, x, cursor, edat);

  edge_mlp_kernel<<<EBLOCKS, 512, 0, stream>>>(edat, PQ, We1 + 256 * 256,
                                               We2T, be2, sums);

  node_fused_kernel<<<NN / 16, 256, 0, stream>>>(h, hn16, sums, cnt,
                                                 Wn1T, bn1, Wn2T, bn2,
                                                 g2, bt2, Wm1T, bm1, Wm2T, bm2, out);
}

// Round 5
// 301.689 us; speedup vs baseline: 1.0816x; 1.0816x over previous
//
#include <hip/hip_runtime.h>

#define NN 10000
#define CC 128
#define HH 256
#define EE 320000
#define ETILE 128
#define EBLOCKS 2500  // EE/128 exact, no pad
#define NBLK 313      // ceil(NN/32); last block has 16 valid nodes

typedef __bf16 bf16_t;
typedef __bf16 bf16x8 __attribute__((ext_vector_type(8)));
typedef __bf16 bf16x4 __attribute__((ext_vector_type(4)));
typedef float f32x4 __attribute__((ext_vector_type(4)));

__device__ __forceinline__ float silu_f(float v) {
#if __has_builtin(__builtin_amdgcn_rcpf)
  return v * __builtin_amdgcn_rcpf(1.0f + __expf(-v));
#else
  return v / (1.0f + __expf(-v));
#endif
}

// ---- GEMM slab helper (16x16x32 bf16 MFMA) ----
// Fragment layouts (guide §3, m89-verified):
//   1st operand: lane holds A[m=lane&15][k=quad*8+j]
//   2nd operand: lane holds B[k=quad*8+j][n=lane&15]
//   C/D: col(n)=lane&15, row(m)=quad*4+reg
template<int RE, int KD, int SA, int NT>
__device__ __forceinline__ void gemm_lg(const bf16_t* sAa, const bf16_t* __restrict__ BT,
                                        int nwavebase, int lr, int quad, f32x4 acc[RE][NT]) {
  for (int kk = 0; kk < KD; kk += 32) {
    bf16x8 a[RE]; bf16x8 b[NT];
#pragma unroll
    for (int re = 0; re < RE; re++)
      a[re] = *(const bf16x8*)(sAa + (re * 16 + lr) * SA + kk + quad * 8);
#pragma unroll
    for (int ce = 0; ce < NT; ce++)
      b[ce] = *(const bf16x8*)(BT + (size_t)(nwavebase + ce * 16 + lr) * KD + kk + quad * 8);
#pragma unroll
    for (int re = 0; re < RE; re++)
#pragma unroll
      for (int ce = 0; ce < NT; ce++)
        acc[re][ce] = __builtin_amdgcn_mfma_f32_16x16x32_bf16(a[re], b[ce], acc[re][ce], 0, 0, 0);
  }
}

// ---------- prep: 6 weight transposes + zero sums/cnt ----------
__global__ __launch_bounds__(256) void prep_kernel(
    const float* __restrict__ We1, const float* __restrict__ We2,
    const float* __restrict__ Wn1, const float* __restrict__ Wn2,
    const float* __restrict__ Wm1, const float* __restrict__ Wm2,
    bf16_t* __restrict__ We1T, bf16_t* __restrict__ We2T,
    bf16_t* __restrict__ Wn1T, bf16_t* __restrict__ Wn2T,
    bf16_t* __restrict__ Wm1T, bf16_t* __restrict__ Wm2T,
    float* __restrict__ sums, int* __restrict__ cnt) {
  int i = blockIdx.x * 256 + threadIdx.x;
  if (i < 327680) {
    const float* src; bf16_t* dst; int K, Nc, idx;
    if      (i < 65536)  { src = We1; dst = We1T; K = 256; Nc = 256; idx = i; }
    else if (i < 131072) { src = We2; dst = We2T; K = 256; Nc = 256; idx = i - 65536; }
    else if (i < 229376) { src = Wn1; dst = Wn1T; K = 384; Nc = 256; idx = i - 131072; }
    else if (i < 262144) { src = Wn2; dst = Wn2T; K = 256; Nc = 128; idx = i - 229376; }
    else if (i < 294912) { src = Wm1; dst = Wm1T; K = 128; Nc = 256; idx = i - 262144; }
    else                 { src = Wm2; dst = Wm2T; K = 256; Nc = 128; idx = i - 294912; }
    int n = idx / K, k = idx - n * K;
    dst[idx] = (bf16_t)src[(size_t)k * Nc + n];
  } else if (i < 327680 + 640000) {  // NN*HH/4 f32x4 zeros
    f32x4 z = {0.f, 0.f, 0.f, 0.f};
    ((f32x4*)sums)[i - 327680] = z;
  } else if (i < 327680 + 640000 + 2500) {  // NN/4 int4 zeros
    int4 z = {0, 0, 0, 0};
    ((int4*)cnt)[i - 967680] = z;
  }
}

// ---------- fused LN1 + P/Q precompute, 32 nodes/block, 313 blocks ----------
// Round-5: 32 nodes/block halves We1T L2 re-reads per node and doubles MFMA
// density (acc[8][2]: 2 MFMA per A-fragment load). LN1: 8 threads/node, 16 ch.
__global__ __launch_bounds__(256, 3) void node_pre_kernel(
    const float* __restrict__ h, const float* __restrict__ g1,
    const float* __restrict__ bt1,
    const bf16_t* __restrict__ We1T, const float* __restrict__ be1,
    bf16_t* __restrict__ hn16, bf16_t* __restrict__ PQ) {
  __shared__ __align__(16) bf16_t sHn[32 * 136];
  int tid = threadIdx.x;
  int lane = tid & 63, wave = tid >> 6;
  int lr = lane & 15, quad = lane >> 4;
  int n0 = blockIdx.x * 32;

  // LN1: 8 threads/node, 16 channels each (8-lane shfl groups stay in-wave)
  {
    int node = tid >> 3, c0 = (tid & 7) * 16;
    bool valid = (n0 + node) < NN;
    size_t base = (size_t)(n0 + node) * CC;
    f32x4 u[4];
#pragma unroll
    for (int j = 0; j < 4; j++)
      u[j] = valid ? *(const f32x4*)(h + base + c0 + j * 4) : f32x4{0.f, 0.f, 0.f, 0.f};
    float s = 0.f, sq = 0.f;
#pragma unroll
    for (int j = 0; j < 4; j++)
#pragma unroll
      for (int r = 0; r < 4; r++) { s += u[j][r]; sq += u[j][r] * u[j][r]; }
#pragma unroll
    for (int o = 4; o > 0; o >>= 1) { s += __shfl_xor(s, o); sq += __shfl_xor(sq, o); }
    float mu = s * (1.0f / CC);
    float var = sq * (1.0f / CC) - mu * mu;
    float rs = rsqrtf(var + 1e-5f);
    bf16x8 ov0, ov1;
#pragma unroll
    for (int j = 0; j < 4; j++) {
      f32x4 gg = *(const f32x4*)(g1 + c0 + j * 4);
      f32x4 bb = *(const f32x4*)(bt1 + c0 + j * 4);
#pragma unroll
      for (int r = 0; r < 4; r++) {
        float o = (u[j][r] - mu) * rs * gg[r] + bb[r];
        if (j < 2) ov0[j * 4 + r] = (bf16_t)o; else ov1[(j - 2) * 4 + r] = (bf16_t)o;
      }
    }
    *(bf16x8*)(sHn + node * 136 + c0) = ov0;
    *(bf16x8*)(sHn + node * 136 + c0 + 8) = ov1;
    if (valid) {
      *(bf16x8*)(hn16 + base + c0) = ov0;
      *(bf16x8*)(hn16 + base + c0 + 8) = ov1;
    }
  }
  __syncthreads();

  // PQ GEMM: waves 0-1 -> P (koff 0), waves 2-3 -> Q (koff 128).
  // Each wave: 128 out-ch (8 re) x 2 node-tiles (32 nodes).
  bool isQ = wave >= 2;
  int rbase = (wave & 1) * 128;
  int koff = isQ ? 128 : 0;
  f32x4 zf = {0.f, 0.f, 0.f, 0.f};
  f32x4 acc[8][2];
#pragma unroll
  for (int i = 0; i < 8; i++) { acc[i][0] = zf; acc[i][1] = zf; }
  for (int kk = 0; kk < 128; kk += 32) {
    bf16x8 b[2];
#pragma unroll
    for (int nt = 0; nt < 2; nt++)
      b[nt] = *(const bf16x8*)(sHn + (nt * 16 + lr) * 136 + kk + quad * 8);
#pragma unroll
    for (int re = 0; re < 8; re++) {
      bf16x8 a = *(const bf16x8*)(We1T + (size_t)(rbase + re * 16 + lr) * 256 + koff + kk + quad * 8);
#pragma unroll
      for (int nt = 0; nt < 2; nt++)
        acc[re][nt] = __builtin_amdgcn_mfma_f32_16x16x32_bf16(a, b[nt], acc[re][nt], 0, 0, 0);
    }
  }
  // C: col = node (nt*16+lr), row = channel rbase + re*16 + quad*4 + r
#pragma unroll
  for (int re = 0; re < 8; re++) {
    int cb = rbase + re * 16 + quad * 4;
    f32x4 bb = isQ ? zf : *(const f32x4*)(be1 + cb);
#pragma unroll
    for (int nt = 0; nt < 2; nt++) {
      int nodev = nt * 16 + lr;
      if (n0 + nodev < NN) {
        bf16x4 o;
#pragma unroll
        for (int r = 0; r < 4; r++) o[r] = (bf16_t)(acc[re][nt][r] + bb[r]);
        *(bf16x4*)(PQ + (size_t)(n0 + nodev) * 512 + (isQ ? 256 : 0) + cb) = o;
      }
    }
  }
}

// ---------- CSR build ----------
__global__ __launch_bounds__(256) void count_kernel(const int* __restrict__ ei, int* __restrict__ cnt) {
  int e = blockIdx.x * 256 + threadIdx.x;
  atomicAdd(&cnt[ei[EE + e]], 1);
}

// single-pass scan: thread owns 10 contiguous elements
__global__ __launch_bounds__(1024) void scan_kernel(const int* __restrict__ cnt, int* __restrict__ cursor) {
  __shared__ int wsum[16];
  int tid = threadIdx.x, wave = tid >> 6, lane = tid & 63;
  int base = tid * 10;
  int v[10]; int S = 0;
#pragma unroll
  for (int j = 0; j < 10; j++) {
    int i = base + j;
    v[j] = (i < NN) ? cnt[i] : 0;
    S += v[j];
  }
  int s = S;
#pragma unroll
  for (int off = 1; off < 64; off <<= 1) { int t = __shfl_up(s, off); if (lane >= off) s += t; }
  if (lane == 63) wsum[wave] = s;
  __syncthreads();
  if (tid < 16) {
    int ws = wsum[tid];
#pragma unroll
    for (int off = 1; off < 16; off <<= 1) { int t = __shfl_up(ws, off); if (tid >= off) ws += t; }
    wsum[tid] = ws;
  }
  __syncthreads();
  int ex = ((wave > 0) ? wsum[wave - 1] : 0) + s - S;  // exclusive prefix of this chunk
#pragma unroll
  for (int j = 0; j < 10; j++) {
    int i = base + j;
    if (i < NN) cursor[i] = ex;
    ex += v[j];
  }
}

__global__ __launch_bounds__(256) void scatter_kernel(const int* __restrict__ ei,
                                                      const float* __restrict__ x,
                                                      int* __restrict__ cursor,
                                                      uint4* __restrict__ edat) {
  int e = blockIdx.x * 256 + threadIdx.x;
  int r = ei[e], c = ei[EE + e];
  float dx = x[3 * r] - x[3 * c];
  float dy = x[3 * r + 1] - x[3 * c + 1];
  float dz = x[3 * r + 2] - x[3 * c + 2];
  float d = sqrtf(dx * dx + dy * dy + dz * dz);
  float cc = (d <= 5.0f) ? 0.5f * (cosf(d * 0.6283185307179586f) + 1.0f) : 0.0f;
  int pos = atomicAdd(&cursor[c], 1);
  uint4 v = {(unsigned)r, (unsigned)c, __float_as_uint(d), __float_as_uint(cc)};
  edat[pos] = v;
}

// ---------- edge kernel: 128-edge tiles (r3 version; best measured 108.8 us).
// r4 lesson: deeper reg-pipelining spilled (WRITE_SIZE 12.4->51.9 MB) -> revert.
__global__ __launch_bounds__(512, 4) void edge_mlp_kernel(
    const uint4* __restrict__ edat, const bf16_t* __restrict__ PQ,
    const float* __restrict__ We1last,
    const bf16_t* __restrict__ We2T, const float* __restrict__ be2,
    float* __restrict__ sums) {
  __shared__ __align__(512) bf16_t sM1[ETILE * 256];  // 64 KB, swizzled rows
  __shared__ int sRow[ETILE], sCol[ETILE];
  __shared__ float sD[ETILE], sCc[ETILE];
  __shared__ unsigned long long sMaskA, sMaskB;
  int tid = threadIdx.x;
  int lane = tid & 63, wave = tid >> 6;
  int lr = lane & 15, quad = lane >> 4;

  // T1 bijective XCD-chunked swizzle (m204): nwg=2500 = 8*312 + 4.
  int bid = blockIdx.x;
  int xcd = bid & 7, rank = bid >> 3;
  int swz = (xcd < 4 ? xcd * 313 : 4 * 313 + (xcd - 4) * 312) + rank;
  int e0 = swz * ETILE;

  if (tid < ETILE) {
    uint4 v = edat[e0 + tid];
    sRow[tid] = (int)v.x; sCol[tid] = (int)v.y;
    sD[tid] = __uint_as_float(v.z); sCc[tid] = __uint_as_float(v.w);
  }
  __syncthreads();

  if (tid < ETILE) {  // waves 0,1 compute segment-boundary masks
    int fl = (tid > 0) && (sCol[tid] != sCol[tid - 1]);
    unsigned long long m = __ballot(fl);
    if (tid == 0) sMaskA = m;       // edges 1..63
    if (tid == 64) sMaskB = m;      // edges 64..127 (bit j = edge 64+j)
  }

  // m1[e][k] = silu(P[row][k] + Q[col][k] + d*wl[k]); 128 edges x 32 chunks
  // = 4096 chunks, 8 iters/thread; swizzled 16B stores into sM1.
#pragma unroll
  for (int i = 0; i < 8; i++) {
    int o = tid + i * 512;
    int e = o >> 5, q = o & 31;
    int k0 = q * 8;
    int row = sRow[e], col = sCol[e];
    float d = sD[e];
    bf16x8 pv = *(const bf16x8*)(PQ + (size_t)row * 512 + k0);
    bf16x8 qv = *(const bf16x8*)(PQ + (size_t)col * 512 + 256 + k0);
    f32x4 wl0 = *(const f32x4*)(We1last + k0);
    f32x4 wl1 = *(const f32x4*)(We1last + k0 + 4);
    bf16x8 m;
#pragma unroll
    for (int j = 0; j < 4; j++) {
      m[j] = (bf16_t)silu_f((float)pv[j] + (float)qv[j] + d * wl0[j]);
      m[j + 4] = (bf16_t)silu_f((float)pv[j + 4] + (float)qv[j + 4] + d * wl1[j]);
    }
    int boff = ((e << 9) + (q << 4)) ^ ((e & 7) << 4);
    *(bf16x8*)((char*)sM1 + boff) = m;
  }
  __syncthreads();

  // GEMM2: m1 (128 x 256) @ We2 -> wave's 32 channels, swizzled A-reads
  f32x4 zf = {0.f, 0.f, 0.f, 0.f};
  f32x4 acc[8][2];
#pragma unroll
  for (int i = 0; i < 8; i++)
#pragma unroll
    for (int j = 0; j < 2; j++) acc[i][j] = zf;
  {
    int nb = wave * 32;
    for (int kk = 0; kk < 256; kk += 32) {
      bf16x8 a[8], b[2];
#pragma unroll
      for (int re = 0; re < 8; re++) {
        int row = re * 16 + lr;
        int boff = ((row << 9) + (kk << 1) + (quad << 4)) ^ ((row & 7) << 4);
        a[re] = *(const bf16x8*)((const char*)sM1 + boff);
      }
#pragma unroll
      for (int ce = 0; ce < 2; ce++)
        b[ce] = *(const bf16x8*)(We2T + (size_t)(nb + ce * 16 + lr) * 256 + kk + quad * 8);
#pragma unroll
      for (int re = 0; re < 8; re++)
#pragma unroll
        for (int ce = 0; ce < 2; ce++)
          acc[re][ce] = __builtin_amdgcn_mfma_f32_16x16x32_bf16(a[re], b[ce], acc[re][ce], 0, 0, 0);
    }
  }

  // in-register epilogue: silu(acc+be2)*cc  (edge e = re*16+quad*4+r)
  float be2v[2];
#pragma unroll
  for (int ce = 0; ce < 2; ce++) be2v[ce] = be2[wave * 32 + ce * 16 + lr];
#pragma unroll
  for (int re = 0; re < 8; re++) {
    f32x4 cc = *(const f32x4*)(sCc + re * 16 + quad * 4);
#pragma unroll
    for (int ce = 0; ce < 2; ce++)
#pragma unroll
      for (int r = 0; r < 4; r++)
        acc[re][ce][r] = silu_f(acc[re][ce][r] + be2v[ce]) * cc[r];
  }

  // register segmented reduction with static tile-skip (wave-uniform branches).
  {
    unsigned long long mA = sMaskA;
    unsigned long long mB = sMaskB;
    int lo = 0;
    while (lo < ETILE) {
      int hi;
      if (lo < 63) {
        unsigned long long t = mA & (~0ull << (lo + 1));
        hi = t ? (__ffsll((long long)t) - 1)
               : (mB ? 64 + __ffsll((long long)mB) - 1 : ETILE);
      } else {
        int rel = lo - 64;  // lo==63 -> rel=-1 -> shift 0 -> all of mB
        unsigned long long t = (rel < 63) ? (mB & (~0ull << (rel + 1))) : 0ull;
        hi = t ? 64 + __ffsll((long long)t) - 1 : ETILE;
      }
      f32x4 tv = zf;
#pragma unroll
      for (int re = 0; re < 8; re++) {
        int t0 = re * 16, t1e = t0 + 16;
        if (t1e <= lo || t0 >= hi) continue;  // tile outside segment (scalar skip)
        if (t0 >= lo && t1e <= hi) {          // tile fully inside: unmasked adds
#pragma unroll
          for (int r = 0; r < 4; r++)
#pragma unroll
            for (int ce = 0; ce < 2; ce++)
              tv[ce] += acc[re][ce][r];
        } else {                              // straddles boundary: masked adds
          int eb = t0 + quad * 4;
#pragma unroll
          for (int r = 0; r < 4; r++) {
            int e = eb + r;
            bool in = (e >= lo) && (e < hi);
#pragma unroll
            for (int ce = 0; ce < 2; ce++)
              tv[ce] += in ? acc[re][ce][r] : 0.0f;
          }
        }
      }
#pragma unroll
      for (int ce = 0; ce < 2; ce++) {
        tv[ce] += __shfl_xor(tv[ce], 16);
        tv[ce] += __shfl_xor(tv[ce], 32);
      }
      if (quad == 0) {
        int colv = sCol[lo];
#pragma unroll
        for (int ce = 0; ce < 2; ce++)
          atomicAdd(&sums[(size_t)colv * HH + wave * 32 + ce * 16 + lr], tv[ce]);
      }
      lo = hi;
    }
  }
}

// ---------- fused node pipeline: 32 nodes/block, 313 blocks ----------
// Round-5: 32 nodes/block halves Wn*/Wm* L2 re-reads per node, doubles MFMA
// density (RE=2). sLn aliased into dead sA1 -> LDS ~59 KB, 2 blocks/CU.
__global__ __launch_bounds__(256, 2) void node_fused_kernel(
    const float* __restrict__ h, const bf16_t* __restrict__ hn16,
    const float* __restrict__ sums, const int* __restrict__ cnt,
    const bf16_t* __restrict__ Wn1T, const float* __restrict__ bn1,
    const bf16_t* __restrict__ Wn2T, const float* __restrict__ bn2,
    const float* __restrict__ g2, const float* __restrict__ bt2,
    const bf16_t* __restrict__ Wm1T, const float* __restrict__ bm1,
    const bf16_t* __restrict__ Wm2T, const float* __restrict__ bm2,
    float* __restrict__ out) {
  __shared__ __align__(16) bf16_t sA1[32 * 392];   // also reused as sLn (stride 136)
  __shared__ __align__(16) bf16_t sM[32 * 264];
  __shared__ __align__(16) float sH1[32 * 132];
  __shared__ float sRc[32];
  int tid = threadIdx.x;
  int lane = tid & 63, wave = tid >> 6;
  int lr = lane & 15, quad = lane >> 4;
  int n0 = blockIdx.x * 32;

  if (tid < 32) sRc[tid] = (n0 + tid < NN) ? 1.0f / fmaxf((float)cnt[n0 + tid], 1.0f) : 1.0f;
  __syncthreads();

  // stage A1 = [hn16 | sums*rc]: 32 nodes x 48 16B-chunks = 1536, 6 iters
#pragma unroll
  for (int i = 0; i < 6; i++) {
    int o = tid + i * 256;
    int e = o / 48, q = o - e * 48;
    int node = n0 + e;
    bool v = node < NN;
    if (q < 16) {
      uint4 z = {0u, 0u, 0u, 0u};
      *(uint4*)(sA1 + e * 392 + q * 8) = v ? *(const uint4*)(hn16 + (size_t)node * CC + q * 8) : z;
    } else {
      float rc = sRc[e];
      const float* sp = sums + (size_t)node * HH + (q - 16) * 8;
      bf16x8 bv;
#pragma unroll
      for (int k2 = 0; k2 < 8; k2++) bv[k2] = v ? (bf16_t)(sp[k2] * rc) : (bf16_t)0.0f;
      *(bf16x8*)(sA1 + e * 392 + 128 + (q - 16) * 8) = bv;
    }
  }
  __syncthreads();

  f32x4 zf = {0.f, 0.f, 0.f, 0.f};
  {  // GEMM1: 32x384 @ 384x256 -> silu -> sM
    f32x4 acc[2][4];
#pragma unroll
    for (int i = 0; i < 2; i++)
#pragma unroll
      for (int j = 0; j < 4; j++) acc[i][j] = zf;
    gemm_lg<2, 384, 392, 4>(sA1, Wn1T, wave * 64, lr, quad, acc);
#pragma unroll
    for (int ce = 0; ce < 4; ce++) {
      int n = wave * 64 + ce * 16 + lr;
      float b1 = bn1[n];
#pragma unroll
      for (int re = 0; re < 2; re++)
#pragma unroll
        for (int r = 0; r < 4; r++)
          sM[(re * 16 + quad * 4 + r) * 264 + n] = (bf16_t)silu_f(acc[re][ce][r] + b1);
    }
  }
  __syncthreads();

  {  // GEMM2: 32x256 @ 256x128; h1 = h + hn + hd -> sH1
    f32x4 acc[2][2];
#pragma unroll
    for (int i = 0; i < 2; i++) { acc[i][0] = zf; acc[i][1] = zf; }
    gemm_lg<2, 256, 264, 2>(sM, Wn2T, wave * 32, lr, quad, acc);
#pragma unroll
    for (int ce = 0; ce < 2; ce++) {
      int n = wave * 32 + ce * 16 + lr;
      float b2 = bn2[n];
#pragma unroll
      for (int re = 0; re < 2; re++)
#pragma unroll
        for (int r = 0; r < 4; r++) {
          int node = re * 16 + quad * 4 + r;
          bool v = (n0 + node) < NN;
          float hv = (float)sA1[node * 392 + n];
          float res = 0.f;
          if (v) res = h[(size_t)(n0 + node) * CC + n] + hv + acc[re][ce][r] + b2;
          sH1[node * 132 + n] = res;
        }
    }
  }
  __syncthreads();

  {  // LN2 in-LDS: 8 threads/node, 16 channels; write into sA1-aliased sLn
    int node = tid >> 3, c0 = (tid & 7) * 16;
    f32x4 u[4];
#pragma unroll
    for (int j = 0; j < 4; j++) u[j] = *(const f32x4*)(sH1 + node * 132 + c0 + j * 4);
    float s = 0.f, sq = 0.f;
#pragma unroll
    for (int j = 0; j < 4; j++)
#pragma unroll
      for (int r = 0; r < 4; r++) { s += u[j][r]; sq += u[j][r] * u[j][r]; }
#pragma unroll
    for (int o = 4; o > 0; o >>= 1) { s += __shfl_xor(s, o); sq += __shfl_xor(sq, o); }
    float mu = s * (1.0f / CC);
    float var = sq * (1.0f / CC) - mu * mu;
    float rs = rsqrtf(var + 1e-5f);
    bf16x8 ov0, ov1;
#pragma unroll
    for (int j = 0; j < 4; j++) {
      f32x4 gg = *(const f32x4*)(g2 + c0 + j * 4);
      f32x4 bb = *(const f32x4*)(bt2 + c0 + j * 4);
#pragma unroll
      for (int r = 0; r < 4; r++) {
        float o = (u[j][r] - mu) * rs * gg[r] + bb[r];
        if (j < 2) ov0[j * 4 + r] = (bf16_t)o; else ov1[(j - 2) * 4 + r] = (bf16_t)o;
      }
    }
    __syncthreads();  // ensure all GEMM2-epilogue sA1 reads done before overwrite
    *(bf16x8*)(sA1 + node * 136 + c0) = ov0;
    *(bf16x8*)(sA1 + node * 136 + c0 + 8) = ov1;
  }
  __syncthreads();

  {  // GEMM3: 32x128 @ 128x256 -> silu -> sM (reuse)
    f32x4 acc[2][4];
#pragma unroll
    for (int i = 0; i < 2; i++)
#pragma unroll
      for (int j = 0; j < 4; j++) acc[i][j] = zf;
    gemm_lg<2, 128, 136, 4>(sA1, Wm1T, wave * 64, lr, quad, acc);
#pragma unroll
    for (int ce = 0; ce < 4; ce++) {
      int n = wave * 64 + ce * 16 + lr;
      float b1 = bm1[n];
#pragma unroll
      for (int re = 0; re < 2; re++)
#pragma unroll
        for (int r = 0; r < 4; r++)
          sM[(re * 16 + quad * 4 + r) * 264 + n] = (bf16_t)silu_f(acc[re][ce][r] + b1);
    }
  }
  __syncthreads();

  {  // GEMM4: 32x256 @ 256x128; out = h1 + hd2
    f32x4 acc[2][2];
#pragma unroll
    for (int i = 0; i < 2; i++) { acc[i][0] = zf; acc[i][1] = zf; }
    gemm_lg<2, 256, 264, 2>(sM, Wm2T, wave * 32, lr, quad, acc);
#pragma unroll
    for (int ce = 0; ce < 2; ce++) {
      int n = wave * 32 + ce * 16 + lr;
      float b2 = bm2[n];
#pragma unroll
      for (int re = 0; re < 2; re++)
#pragma unroll
        for (int r = 0; r < 4; r++) {
          int node = re * 16 + quad * 4 + r;
          if ((n0 + node) < NN)
            out[(size_t)(n0 + node) * CC + n] = sH1[node * 132 + n] + acc[re][ce][r] + b2;
        }
    }
  }
}

extern "C" void kernel_launch(void* const* d_in, const int* in_sizes, int n_in,
                              void* d_out, int out_size, void* d_ws, size_t ws_size,
                              hipStream_t stream) {
  const float* x    = (const float*)d_in[0];
  const float* h    = (const float*)d_in[1];
  const int*   ei   = (const int*)d_in[2];
  const float* We1  = (const float*)d_in[3];
  const float* be1  = (const float*)d_in[4];
  const float* We2  = (const float*)d_in[5];
  const float* be2  = (const float*)d_in[6];
  const float* Wn1  = (const float*)d_in[7];
  const float* bn1  = (const float*)d_in[8];
  const float* Wn2  = (const float*)d_in[9];
  const float* bn2  = (const float*)d_in[10];
  const float* Wm1  = (const float*)d_in[11];
  const float* bm1  = (const float*)d_in[12];
  const float* Wm2  = (const float*)d_in[13];
  const float* bm2  = (const float*)d_in[14];
  const float* g1   = (const float*)d_in[15];
  const float* bt1  = (const float*)d_in[16];
  const float* g2   = (const float*)d_in[17];
  const float* bt2  = (const float*)d_in[18];
  float* out = (float*)d_out;

  char* wp = (char*)d_ws;
  size_t off = 0;
  auto alloc = [&](size_t bytes) -> void* {
    void* p = wp + off;
    off = (off + bytes + 255) & ~(size_t)255;
    return p;
  };

  bf16_t* hn16   = (bf16_t*)alloc((size_t)NN * CC * 2);
  bf16_t* PQ     = (bf16_t*)alloc((size_t)NN * 512 * 2);
  float*  sums   = (float*)alloc((size_t)NN * HH * 4);
  int*    cnt    = (int*)alloc((size_t)NN * 4);
  int*    cursor = (int*)alloc((size_t)NN * 4);
  uint4*  edat   = (uint4*)alloc((size_t)EE * 16);
  bf16_t* We1T   = (bf16_t*)alloc(256 * 256 * 2);
  bf16_t* We2T   = (bf16_t*)alloc(256 * 256 * 2);
  bf16_t* Wn1T   = (bf16_t*)alloc(256 * 384 * 2);
  bf16_t* Wn2T   = (bf16_t*)alloc(128 * 256 * 2);
  bf16_t* Wm1T   = (bf16_t*)alloc(256 * 128 * 2);
  bf16_t* Wm2T   = (bf16_t*)alloc(128 * 256 * 2);

  prep_kernel<<<3791, 256, 0, stream>>>(We1, We2, Wn1, Wn2, Wm1, Wm2,
                                        We1T, We2T, Wn1T, Wn2T, Wm1T, Wm2T,
                                        sums, cnt);

  node_pre_kernel<<<NBLK, 256, 0, stream>>>(h, g1, bt1, We1T, be1, hn16, PQ);

  count_kernel<<<EE / 256, 256, 0, stream>>>(ei, cnt);
  scan_kernel<<<1, 1024, 0, stream>>>(cnt, cursor);
  scatter_kernel<<<EE / 256, 256, 0, stream>>>(ei, x, cursor, edat);

  edge_mlp_kernel<<<EBLOCKS, 512, 0, stream>>>(edat, PQ, We1 + 256 * 256,
                                               We2T, be2, sums);

  node_fused_kernel<<<NBLK, 256, 0, stream>>>(h, hn16, sums, cnt,
                                              Wn1T, bn1, Wn2T, bn2,
                                              g2, bt2, Wm1T, bm1, Wm2T, bm2, out);
}

// Round 6
// 296.384 us; speedup vs baseline: 1.1009x; 1.0179x over previous
//
#include <hip/hip_runtime.h>

#define NN 10000
#define CC 128
#define HH 256
#define EE 320000
#define ETILE 128
#define EBLOCKS 2500  // EE/128 exact, no pad

typedef __bf16 bf16_t;
typedef __bf16 bf16x8 __attribute__((ext_vector_type(8)));
typedef __bf16 bf16x4 __attribute__((ext_vector_type(4)));
typedef float f32x4 __attribute__((ext_vector_type(4)));

__device__ __forceinline__ float silu_f(float v) {
#if __has_builtin(__builtin_amdgcn_rcpf)
  return v * __builtin_amdgcn_rcpf(1.0f + __expf(-v));
#else
  return v / (1.0f + __expf(-v));
#endif
}

// ---- GEMM slab helper (16x16x32 bf16 MFMA) ----
// Fragment layouts (guide §3, m89-verified):
//   1st operand: lane holds A[m=lane&15][k=quad*8+j]
//   2nd operand: lane holds B[k=quad*8+j][n=lane&15]
//   C/D: col(n)=lane&15, row(m)=quad*4+reg
template<int RE, int KD, int SA, int NT>
__device__ __forceinline__ void gemm_lg(const bf16_t* sAa, const bf16_t* __restrict__ BT,
                                        int nwavebase, int lr, int quad, f32x4 acc[RE][NT]) {
  for (int kk = 0; kk < KD; kk += 32) {
    bf16x8 a[RE]; bf16x8 b[NT];
#pragma unroll
    for (int re = 0; re < RE; re++)
      a[re] = *(const bf16x8*)(sAa + (re * 16 + lr) * SA + kk + quad * 8);
#pragma unroll
    for (int ce = 0; ce < NT; ce++)
      b[ce] = *(const bf16x8*)(BT + (size_t)(nwavebase + ce * 16 + lr) * KD + kk + quad * 8);
#pragma unroll
    for (int re = 0; re < RE; re++)
#pragma unroll
      for (int ce = 0; ce < NT; ce++)
        acc[re][ce] = __builtin_amdgcn_mfma_f32_16x16x32_bf16(a[re], b[ce], acc[re][ce], 0, 0, 0);
  }
}

// ---------- prep: 6 weight transposes only (sums/cnt zeroed via memsetAsync) ----------
__global__ __launch_bounds__(256) void prep_kernel(
    const float* __restrict__ We1, const float* __restrict__ We2,
    const float* __restrict__ Wn1, const float* __restrict__ Wn2,
    const float* __restrict__ Wm1, const float* __restrict__ Wm2,
    bf16_t* __restrict__ We1T, bf16_t* __restrict__ We2T,
    bf16_t* __restrict__ Wn1T, bf16_t* __restrict__ Wn2T,
    bf16_t* __restrict__ Wm1T, bf16_t* __restrict__ Wm2T) {
  int i = blockIdx.x * 256 + threadIdx.x;
  if (i < 327680) {
    const float* src; bf16_t* dst; int K, Nc, idx;
    if      (i < 65536)  { src = We1; dst = We1T; K = 256; Nc = 256; idx = i; }
    else if (i < 131072) { src = We2; dst = We2T; K = 256; Nc = 256; idx = i - 65536; }
    else if (i < 229376) { src = Wn1; dst = Wn1T; K = 384; Nc = 256; idx = i - 131072; }
    else if (i < 262144) { src = Wn2; dst = Wn2T; K = 256; Nc = 128; idx = i - 229376; }
    else if (i < 294912) { src = Wm1; dst = Wm1T; K = 128; Nc = 256; idx = i - 262144; }
    else                 { src = Wm2; dst = Wm2T; K = 256; Nc = 128; idx = i - 294912; }
    int n = idx / K, k = idx - n * K;
    dst[idx] = (bf16_t)src[(size_t)k * Nc + n];
  }
}

// ---------- fused LN1 + P/Q precompute (r0 16-node version) + count fusion ----------
// blocks 0..624: hn = LN(h,g1,bt1) -> hn16; PQ = [hn@We1_P + be1 | hn@We1_Q]
// blocks 625..1874: count_kernel work (independent; saves a launch)
__global__ __launch_bounds__(256, 4) void node_pre_kernel(
    const float* __restrict__ h, const float* __restrict__ g1,
    const float* __restrict__ bt1,
    const bf16_t* __restrict__ We1T, const float* __restrict__ be1,
    bf16_t* __restrict__ hn16, bf16_t* __restrict__ PQ,
    const int* __restrict__ ei, int* __restrict__ cnt) {
  __shared__ __align__(16) bf16_t sHn[16 * 136];
  int tid = threadIdx.x;
  if (blockIdx.x >= 625) {  // fused edge-count
    int e = (blockIdx.x - 625) * 256 + tid;
    atomicAdd(&cnt[ei[EE + e]], 1);
    return;
  }
  int lane = tid & 63, wave = tid >> 6;
  int lr = lane & 15, quad = lane >> 4;
  int n0 = blockIdx.x * 16;  // 625 * 16 = NN exact

  // LN1: 16 threads/node, 8 channels each
  {
    int node = tid >> 4, c0 = (tid & 15) * 8;
    size_t base = (size_t)(n0 + node) * CC;
    f32x4 u0 = *(const f32x4*)(h + base + c0);
    f32x4 u1 = *(const f32x4*)(h + base + c0 + 4);
    float s = 0.f, sq = 0.f;
#pragma unroll
    for (int j = 0; j < 4; j++) { s += u0[j] + u1[j]; sq += u0[j] * u0[j] + u1[j] * u1[j]; }
#pragma unroll
    for (int o = 8; o > 0; o >>= 1) { s += __shfl_xor(s, o); sq += __shfl_xor(sq, o); }
    float mu = s * (1.0f / CC);
    float var = sq * (1.0f / CC) - mu * mu;
    float rs = rsqrtf(var + 1e-5f);
    f32x4 gg0 = *(const f32x4*)(g1 + c0), gg1 = *(const f32x4*)(g1 + c0 + 4);
    f32x4 bb0 = *(const f32x4*)(bt1 + c0), bb1 = *(const f32x4*)(bt1 + c0 + 4);
    bf16x8 ov;
#pragma unroll
    for (int j = 0; j < 4; j++) {
      ov[j] = (bf16_t)((u0[j] - mu) * rs * gg0[j] + bb0[j]);
      ov[j + 4] = (bf16_t)((u1[j] - mu) * rs * gg1[j] + bb1[j]);
    }
    *(bf16x8*)(sHn + node * 136 + c0) = ov;
    *(bf16x8*)(hn16 + base + c0) = ov;
  }
  __syncthreads();

  // PQ GEMM: waves 0-1 -> P (We1T k-cols 0:128), waves 2-3 -> Q (k-cols 128:256).
  bool isQ = wave >= 2;
  int rbase = (wave & 1) * 128;
  int koff = isQ ? 128 : 0;
  f32x4 zf = {0.f, 0.f, 0.f, 0.f};
  f32x4 acc[8];
#pragma unroll
  for (int i = 0; i < 8; i++) acc[i] = zf;
  for (int kk = 0; kk < 128; kk += 32) {
    bf16x8 b = *(const bf16x8*)(sHn + lr * 136 + kk + quad * 8);
    bf16x8 a[8];
#pragma unroll
    for (int re = 0; re < 8; re++)
      a[re] = *(const bf16x8*)(We1T + (size_t)(rbase + re * 16 + lr) * 256 + koff + kk + quad * 8);
#pragma unroll
    for (int re = 0; re < 8; re++)
      acc[re] = __builtin_amdgcn_mfma_f32_16x16x32_bf16(a[re], b, acc[re], 0, 0, 0);
  }
  // C: col = node (lr), row = channel rbase + re*16 + quad*4 + r
#pragma unroll
  for (int re = 0; re < 8; re++) {
    int cb = rbase + re * 16 + quad * 4;
    f32x4 bb = isQ ? zf : *(const f32x4*)(be1 + cb);
    bf16x4 o;
#pragma unroll
    for (int r = 0; r < 4; r++) o[r] = (bf16_t)(acc[re][r] + bb[r]);
    *(bf16x4*)(PQ + (size_t)(n0 + lr) * 512 + (isQ ? 256 : 0) + cb) = o;
  }
}

// single-pass scan: thread owns 10 contiguous elements
__global__ __launch_bounds__(1024) void scan_kernel(const int* __restrict__ cnt, int* __restrict__ cursor) {
  __shared__ int wsum[16];
  int tid = threadIdx.x, wave = tid >> 6, lane = tid & 63;
  int base = tid * 10;
  int v[10]; int S = 0;
#pragma unroll
  for (int j = 0; j < 10; j++) {
    int i = base + j;
    v[j] = (i < NN) ? cnt[i] : 0;
    S += v[j];
  }
  int s = S;
#pragma unroll
  for (int off = 1; off < 64; off <<= 1) { int t = __shfl_up(s, off); if (lane >= off) s += t; }
  if (lane == 63) wsum[wave] = s;
  __syncthreads();
  if (tid < 16) {
    int ws = wsum[tid];
#pragma unroll
    for (int off = 1; off < 16; off <<= 1) { int t = __shfl_up(ws, off); if (tid >= off) ws += t; }
    wsum[tid] = ws;
  }
  __syncthreads();
  int ex = ((wave > 0) ? wsum[wave - 1] : 0) + s - S;  // exclusive prefix of this chunk
#pragma unroll
  for (int j = 0; j < 10; j++) {
    int i = base + j;
    if (i < NN) cursor[i] = ex;
    ex += v[j];
  }
}

__global__ __launch_bounds__(256) void scatter_kernel(const int* __restrict__ ei,
                                                      const float* __restrict__ x,
                                                      int* __restrict__ cursor,
                                                      uint4* __restrict__ edat) {
  int e = blockIdx.x * 256 + threadIdx.x;
  int r = ei[e], c = ei[EE + e];
  float dx = x[3 * r] - x[3 * c];
  float dy = x[3 * r + 1] - x[3 * c + 1];
  float dz = x[3 * r + 2] - x[3 * c + 2];
  float d = sqrtf(dx * dx + dy * dy + dz * dz);
  float cc = (d <= 5.0f) ? 0.5f * (__cosf(d * 0.6283185307179586f) + 1.0f) : 0.0f;
  int pos = atomicAdd(&cursor[c], 1);
  uint4 v = {(unsigned)r, (unsigned)c, __float_as_uint(d), __float_as_uint(cc)};
  edat[pos] = v;
}

// ---------- edge kernel: 128-edge tiles (r3/r5 version; steady 109 us) ----------
__global__ __launch_bounds__(512, 4) void edge_mlp_kernel(
    const uint4* __restrict__ edat, const bf16_t* __restrict__ PQ,
    const float* __restrict__ We1last,
    const bf16_t* __restrict__ We2T, const float* __restrict__ be2,
    float* __restrict__ sums) {
  __shared__ __align__(512) bf16_t sM1[ETILE * 256];  // 64 KB, swizzled rows
  __shared__ int sRow[ETILE], sCol[ETILE];
  __shared__ float sD[ETILE], sCc[ETILE];
  __shared__ unsigned long long sMaskA, sMaskB;
  int tid = threadIdx.x;
  int lane = tid & 63, wave = tid >> 6;
  int lr = lane & 15, quad = lane >> 4;

  // T1 bijective XCD-chunked swizzle (m204): nwg=2500 = 8*312 + 4.
  int bid = blockIdx.x;
  int xcd = bid & 7, rank = bid >> 3;
  int swz = (xcd < 4 ? xcd * 313 : 4 * 313 + (xcd - 4) * 312) + rank;
  int e0 = swz * ETILE;

  if (tid < ETILE) {
    uint4 v = edat[e0 + tid];
    sRow[tid] = (int)v.x; sCol[tid] = (int)v.y;
    sD[tid] = __uint_as_float(v.z); sCc[tid] = __uint_as_float(v.w);
  }
  __syncthreads();

  if (tid < ETILE) {  // waves 0,1 compute segment-boundary masks
    int fl = (tid > 0) && (sCol[tid] != sCol[tid - 1]);
    unsigned long long m = __ballot(fl);
    if (tid == 0) sMaskA = m;       // edges 1..63
    if (tid == 64) sMaskB = m;      // edges 64..127 (bit j = edge 64+j)
  }

  // m1[e][k] = silu(P[row][k] + Q[col][k] + d*wl[k]); 128 edges x 32 chunks
#pragma unroll
  for (int i = 0; i < 8; i++) {
    int o = tid + i * 512;
    int e = o >> 5, q = o & 31;
    int k0 = q * 8;
    int row = sRow[e], col = sCol[e];
    float d = sD[e];
    bf16x8 pv = *(const bf16x8*)(PQ + (size_t)row * 512 + k0);
    bf16x8 qv = *(const bf16x8*)(PQ + (size_t)col * 512 + 256 + k0);
    f32x4 wl0 = *(const f32x4*)(We1last + k0);
    f32x4 wl1 = *(const f32x4*)(We1last + k0 + 4);
    bf16x8 m;
#pragma unroll
    for (int j = 0; j < 4; j++) {
      m[j] = (bf16_t)silu_f((float)pv[j] + (float)qv[j] + d * wl0[j]);
      m[j + 4] = (bf16_t)silu_f((float)pv[j + 4] + (float)qv[j + 4] + d * wl1[j]);
    }
    int boff = ((e << 9) + (q << 4)) ^ ((e & 7) << 4);
    *(bf16x8*)((char*)sM1 + boff) = m;
  }
  __syncthreads();

  // GEMM2: m1 (128 x 256) @ We2 -> wave's 32 channels, swizzled A-reads
  f32x4 zf = {0.f, 0.f, 0.f, 0.f};
  f32x4 acc[8][2];
#pragma unroll
  for (int i = 0; i < 8; i++)
#pragma unroll
    for (int j = 0; j < 2; j++) acc[i][j] = zf;
  {
    int nb = wave * 32;
    for (int kk = 0; kk < 256; kk += 32) {
      bf16x8 a[8], b[2];
#pragma unroll
      for (int re = 0; re < 8; re++) {
        int row = re * 16 + lr;
        int boff = ((row << 9) + (kk << 1) + (quad << 4)) ^ ((row & 7) << 4);
        a[re] = *(const bf16x8*)((const char*)sM1 + boff);
      }
#pragma unroll
      for (int ce = 0; ce < 2; ce++)
        b[ce] = *(const bf16x8*)(We2T + (size_t)(nb + ce * 16 + lr) * 256 + kk + quad * 8);
#pragma unroll
      for (int re = 0; re < 8; re++)
#pragma unroll
        for (int ce = 0; ce < 2; ce++)
          acc[re][ce] = __builtin_amdgcn_mfma_f32_16x16x32_bf16(a[re], b[ce], acc[re][ce], 0, 0, 0);
    }
  }

  // in-register epilogue: silu(acc+be2)*cc  (edge e = re*16+quad*4+r)
  float be2v[2];
#pragma unroll
  for (int ce = 0; ce < 2; ce++) be2v[ce] = be2[wave * 32 + ce * 16 + lr];
#pragma unroll
  for (int re = 0; re < 8; re++) {
    f32x4 cc = *(const f32x4*)(sCc + re * 16 + quad * 4);
#pragma unroll
    for (int ce = 0; ce < 2; ce++)
#pragma unroll
      for (int r = 0; r < 4; r++)
        acc[re][ce][r] = silu_f(acc[re][ce][r] + be2v[ce]) * cc[r];
  }

  // register segmented reduction with static tile-skip (wave-uniform branches).
  {
    unsigned long long mA = sMaskA;
    unsigned long long mB = sMaskB;
    int lo = 0;
    while (lo < ETILE) {
      int hi;
      if (lo < 63) {
        unsigned long long t = mA & (~0ull << (lo + 1));
        hi = t ? (__ffsll((long long)t) - 1)
               : (mB ? 64 + __ffsll((long long)mB) - 1 : ETILE);
      } else {
        int rel = lo - 64;  // lo==63 -> rel=-1 -> shift 0 -> all of mB
        unsigned long long t = (rel < 63) ? (mB & (~0ull << (rel + 1))) : 0ull;
        hi = t ? 64 + __ffsll((long long)t) - 1 : ETILE;
      }
      f32x4 tv = zf;
#pragma unroll
      for (int re = 0; re < 8; re++) {
        int t0 = re * 16, t1e = t0 + 16;
        if (t1e <= lo || t0 >= hi) continue;  // tile outside segment (scalar skip)
        if (t0 >= lo && t1e <= hi) {          // tile fully inside: unmasked adds
#pragma unroll
          for (int r = 0; r < 4; r++)
#pragma unroll
            for (int ce = 0; ce < 2; ce++)
              tv[ce] += acc[re][ce][r];
        } else {                              // straddles boundary: masked adds
          int eb = t0 + quad * 4;
#pragma unroll
          for (int r = 0; r < 4; r++) {
            int e = eb + r;
            bool in = (e >= lo) && (e < hi);
#pragma unroll
            for (int ce = 0; ce < 2; ce++)
              tv[ce] += in ? acc[re][ce][r] : 0.0f;
          }
        }
      }
#pragma unroll
      for (int ce = 0; ce < 2; ce++) {
        tv[ce] += __shfl_xor(tv[ce], 16);
        tv[ce] += __shfl_xor(tv[ce], 32);
      }
      if (quad == 0) {
        int colv = sCol[lo];
#pragma unroll
        for (int ce = 0; ce < 2; ce++)
          atomicAdd(&sums[(size_t)colv * HH + wave * 32 + ce * 16 + lr], tv[ce]);
      }
      lo = hi;
    }
  }
}

// ---------- fused node pipeline (r0 16-node version): 625 blocks ----------
__global__ __launch_bounds__(256, 3) void node_fused_kernel(
    const float* __restrict__ h, const bf16_t* __restrict__ hn16,
    const float* __restrict__ sums, const int* __restrict__ cnt,
    const bf16_t* __restrict__ Wn1T, const float* __restrict__ bn1,
    const bf16_t* __restrict__ Wn2T, const float* __restrict__ bn2,
    const float* __restrict__ g2, const float* __restrict__ bt2,
    const bf16_t* __restrict__ Wm1T, const float* __restrict__ bm1,
    const bf16_t* __restrict__ Wm2T, const float* __restrict__ bm2,
    float* __restrict__ out) {
  __shared__ __align__(16) bf16_t sA1[16 * 392];
  __shared__ __align__(16) bf16_t sM[16 * 264];
  __shared__ __align__(16) float sH1[16 * 132];
  __shared__ __align__(16) bf16_t sLn[16 * 136];
  __shared__ float sRc[16];
  int tid = threadIdx.x;
  int lane = tid & 63, wave = tid >> 6;
  int lr = lane & 15, quad = lane >> 4;
  int n0 = blockIdx.x * 16;  // exact

  if (tid < 16) sRc[tid] = 1.0f / fmaxf((float)cnt[n0 + tid], 1.0f);
  __syncthreads();

  // stage A1 = [hn16 | sums*rc]: 16 nodes x 48 16B-chunks
#pragma unroll
  for (int i = 0; i < 3; i++) {
    int o = tid + i * 256;
    int e = o / 48, q = o - e * 48;
    int node = n0 + e;
    if (q < 16) {
      *(uint4*)(sA1 + e * 392 + q * 8) = *(const uint4*)(hn16 + (size_t)node * CC + q * 8);
    } else {
      float rc = sRc[e];
      const float* sp = sums + (size_t)node * HH + (q - 16) * 8;
      bf16x8 bv;
#pragma unroll
      for (int k2 = 0; k2 < 8; k2++) bv[k2] = (bf16_t)(sp[k2] * rc);
      *(bf16x8*)(sA1 + e * 392 + 128 + (q - 16) * 8) = bv;
    }
  }
  __syncthreads();

  f32x4 zf = {0.f, 0.f, 0.f, 0.f};
  {  // GEMM1: 16x384 @ 384x256 -> silu -> sM
    f32x4 acc[1][4];
#pragma unroll
    for (int j = 0; j < 4; j++) acc[0][j] = zf;
    gemm_lg<1, 384, 392, 4>(sA1, Wn1T, wave * 64, lr, quad, acc);
#pragma unroll
    for (int ce = 0; ce < 4; ce++) {
      int n = wave * 64 + ce * 16 + lr;
      float b1 = bn1[n];
#pragma unroll
      for (int r = 0; r < 4; r++)
        sM[(quad * 4 + r) * 264 + n] = (bf16_t)silu_f(acc[0][ce][r] + b1);
    }
  }
  __syncthreads();

  {  // GEMM2: 16x256 @ 256x128; h1 = h + hn + hd -> sH1
    f32x4 acc[1][2];
    acc[0][0] = zf; acc[0][1] = zf;
    gemm_lg<1, 256, 264, 2>(sM, Wn2T, wave * 32, lr, quad, acc);
#pragma unroll
    for (int ce = 0; ce < 2; ce++) {
      int n = wave * 32 + ce * 16 + lr;
      float b2 = bn2[n];
#pragma unroll
      for (int r = 0; r < 4; r++) {
        int node = quad * 4 + r;
        size_t idx = (size_t)(n0 + node) * CC + n;
        float hn_v = (float)sA1[node * 392 + n];
        sH1[node * 132 + n] = h[idx] + hn_v + acc[0][ce][r] + b2;
      }
    }
  }
  __syncthreads();

  {  // LN2 in-LDS: thread -> node tid>>4, channels (tid&15)*8..+7
    int node = tid >> 4, c0 = (tid & 15) * 8;
    f32x4 u0 = *(const f32x4*)(sH1 + node * 132 + c0);
    f32x4 u1 = *(const f32x4*)(sH1 + node * 132 + c0 + 4);
    float s = 0.f, sq = 0.f;
#pragma unroll
    for (int j = 0; j < 4; j++) { s += u0[j] + u1[j]; sq += u0[j] * u0[j] + u1[j] * u1[j]; }
#pragma unroll
    for (int o = 8; o > 0; o >>= 1) { s += __shfl_xor(s, o); sq += __shfl_xor(sq, o); }
    float mu = s * (1.0f / CC);
    float var = sq * (1.0f / CC) - mu * mu;
    float rs = rsqrtf(var + 1e-5f);
    f32x4 gg0 = *(const f32x4*)(g2 + c0), gg1 = *(const f32x4*)(g2 + c0 + 4);
    f32x4 bb0 = *(const f32x4*)(bt2 + c0), bb1 = *(const f32x4*)(bt2 + c0 + 4);
    bf16x8 ov;
#pragma unroll
    for (int j = 0; j < 4; j++) {
      ov[j] = (bf16_t)((u0[j] - mu) * rs * gg0[j] + bb0[j]);
      ov[j + 4] = (bf16_t)((u1[j] - mu) * rs * gg1[j] + bb1[j]);
    }
    *(bf16x8*)(sLn + node * 136 + c0) = ov;
  }
  __syncthreads();

  {  // GEMM3: 16x128 @ 128x256 -> silu -> sM (reuse)
    f32x4 acc[1][4];
#pragma unroll
    for (int j = 0; j < 4; j++) acc[0][j] = zf;
    gemm_lg<1, 128, 136, 4>(sLn, Wm1T, wave * 64, lr, quad, acc);
#pragma unroll
    for (int ce = 0; ce < 4; ce++) {
      int n = wave * 64 + ce * 16 + lr;
      float b1 = bm1[n];
#pragma unroll
      for (int r = 0; r < 4; r++)
        sM[(quad * 4 + r) * 264 + n] = (bf16_t)silu_f(acc[0][ce][r] + b1);
    }
  }
  __syncthreads();

  {  // GEMM4: 16x256 @ 256x128; out = h1 + hd2
    f32x4 acc[1][2];
    acc[0][0] = zf; acc[0][1] = zf;
    gemm_lg<1, 256, 264, 2>(sM, Wm2T, wave * 32, lr, quad, acc);
#pragma unroll
    for (int ce = 0; ce < 2; ce++) {
      int n = wave * 32 + ce * 16 + lr;
      float b2 = bm2[n];
#pragma unroll
      for (int r = 0; r < 4; r++) {
        int node = quad * 4 + r;
        size_t idx = (size_t)(n0 + node) * CC + n;
        out[idx] = sH1[node * 132 + n] + acc[0][ce][r] + b2;
      }
    }
  }
}

extern "C" void kernel_launch(void* const* d_in, const int* in_sizes, int n_in,
                              void* d_out, int out_size, void* d_ws, size_t ws_size,
                              hipStream_t stream) {
  const float* x    = (const float*)d_in[0];
  const float* h    = (const float*)d_in[1];
  const int*   ei   = (const int*)d_in[2];
  const float* We1  = (const float*)d_in[3];
  const float* be1  = (const float*)d_in[4];
  const float* We2  = (const float*)d_in[5];
  const float* be2  = (const float*)d_in[6];
  const float* Wn1  = (const float*)d_in[7];
  const float* bn1  = (const float*)d_in[8];
  const float* Wn2  = (const float*)d_in[9];
  const float* bn2  = (const float*)d_in[10];
  const float* Wm1  = (const float*)d_in[11];
  const float* bm1  = (const float*)d_in[12];
  const float* Wm2  = (const float*)d_in[13];
  const float* bm2  = (const float*)d_in[14];
  const float* g1   = (const float*)d_in[15];
  const float* bt1  = (const float*)d_in[16];
  const float* g2   = (const float*)d_in[17];
  const float* bt2  = (const float*)d_in[18];
  float* out = (float*)d_out;

  char* wp = (char*)d_ws;
  size_t off = 0;
  auto alloc = [&](size_t bytes) -> void* {
    void* p = wp + off;
    off = (off + bytes + 255) & ~(size_t)255;
    return p;
  };

  bf16_t* hn16   = (bf16_t*)alloc((size_t)NN * CC * 2);
  bf16_t* PQ     = (bf16_t*)alloc((size_t)NN * 512 * 2);
  float*  sums   = (float*)alloc((size_t)NN * HH * 4);
  int*    cnt    = (int*)alloc((size_t)NN * 4);
  int*    cursor = (int*)alloc((size_t)NN * 4);
  uint4*  edat   = (uint4*)alloc((size_t)EE * 16);
  bf16_t* We1T   = (bf16_t*)alloc(256 * 256 * 2);
  bf16_t* We2T   = (bf16_t*)alloc(256 * 256 * 2);
  bf16_t* Wn1T   = (bf16_t*)alloc(256 * 384 * 2);
  bf16_t* Wn2T   = (bf16_t*)alloc(128 * 256 * 2);
  bf16_t* Wm1T   = (bf16_t*)alloc(256 * 128 * 2);
  bf16_t* Wm2T   = (bf16_t*)alloc(128 * 256 * 2);

  // zero sums/cnt via DMA memset (capture-safe; replaces 2540 prep blocks)
  hipMemsetAsync(sums, 0, (size_t)NN * HH * 4, stream);
  hipMemsetAsync(cnt, 0, (size_t)NN * 4, stream);

  prep_kernel<<<1280, 256, 0, stream>>>(We1, We2, Wn1, Wn2, Wm1, Wm2,
                                        We1T, We2T, Wn1T, Wn2T, Wm1T, Wm2T);

  // node_pre (625 blocks) + fused count (1250 blocks)
  node_pre_kernel<<<1875, 256, 0, stream>>>(h, g1, bt1, We1T, be1, hn16, PQ,
                                            ei, cnt);

  scan_kernel<<<1, 1024, 0, stream>>>(cnt, cursor);
  scatter_kernel<<<EE / 256, 256, 0, stream>>>(ei, x, cursor, edat);

  edge_mlp_kernel<<<EBLOCKS, 512, 0, stream>>>(edat, PQ, We1 + 256 * 256,
                                               We2T, be2, sums);

  node_fused_kernel<<<NN / 16, 256, 0, stream>>>(h, hn16, sums, cnt,
                                                 Wn1T, bn1, Wn2T, bn2,
                                                 g2, bt2, Wm1T, bm1, Wm2T, bm2, out);
}